// Round 6
// baseline (7811.475 us; speedup 1.0000x reference)
//
#include <hip/hip_runtime.h>
#include <math.h>

#define HID   256
#define GATES 1024   // 4*HID
#define BATCH 64
#define SEQ   2048

// ---------------------------------------------------------------------------
// GEMM: out[r][g] = sum_k A_row(r)[k] * W[g][k] + bias[g]   (unchanged, proven)
// ---------------------------------------------------------------------------
#define BM 128
#define BN 128
#define BK 16
#define LDP 132

__global__ __launch_bounds__(256, 2)
void xg_gemm(const float* __restrict__ A, const float* __restrict__ W,
             const float* __restrict__ bias, float* __restrict__ out,
             int a_bstride, int ch_log2)
{
    __shared__ float As[BK][LDP];
    __shared__ float Ws[BK][LDP];

    const int tid   = threadIdx.x;
    const int m_blk = blockIdx.x * BM;
    const int n_blk = blockIdx.y * BN;

    const int tn = (tid & 15) * 4;
    const int tm = (tid >> 4) * 4;

    float acc[8][8];
    #pragma unroll
    for (int i = 0; i < 8; ++i)
        #pragma unroll
        for (int j = 0; j < 8; ++j) acc[i][j] = 0.f;

    const int lrow = tid >> 2;
    const int lkc  = (tid & 3) * 4;
    const int CHm1 = (1 << ch_log2) - 1;

    for (int k0 = 0; k0 < HID; k0 += BK) {
        #pragma unroll
        for (int p = 0; p < 2; ++p) {
            int row = p * 64 + lrow;
            int r   = m_blk + row;
            int b   = r >> ch_log2;
            int t   = r & CHm1;
            const float4 a = *(const float4*)(A + (size_t)b * a_bstride +
                                              (size_t)t * HID + k0 + lkc);
            As[lkc + 0][row] = a.x;
            As[lkc + 1][row] = a.y;
            As[lkc + 2][row] = a.z;
            As[lkc + 3][row] = a.w;

            int g = n_blk + row;
            const float4 w = *(const float4*)(W + (size_t)g * HID + k0 + lkc);
            Ws[lkc + 0][row] = w.x;
            Ws[lkc + 1][row] = w.y;
            Ws[lkc + 2][row] = w.z;
            Ws[lkc + 3][row] = w.w;
        }
        __syncthreads();

        #pragma unroll
        for (int kk = 0; kk < BK; ++kk) {
            float4 a0 = *(const float4*)&As[kk][tm];
            float4 a1 = *(const float4*)&As[kk][tm + 64];
            float4 b0 = *(const float4*)&Ws[kk][tn];
            float4 b1 = *(const float4*)&Ws[kk][tn + 64];
            float av[8] = {a0.x, a0.y, a0.z, a0.w, a1.x, a1.y, a1.z, a1.w};
            float bv[8] = {b0.x, b0.y, b0.z, b0.w, b1.x, b1.y, b1.z, b1.w};
            #pragma unroll
            for (int i = 0; i < 8; ++i)
                #pragma unroll
                for (int j = 0; j < 8; ++j)
                    acc[i][j] += av[i] * bv[j];
        }
        __syncthreads();
    }

    const float4 bias0 = *(const float4*)&bias[n_blk + tn];
    const float4 bias1 = *(const float4*)&bias[n_blk + tn + 64];
    #pragma unroll
    for (int i = 0; i < 8; ++i) {
        int m  = (i < 4) ? (tm + i) : (tm + 60 + i);
        int gm = m_blk + m;
        float* op = out + (size_t)gm * GATES + n_blk;
        float4 v0 = {acc[i][0] + bias0.x, acc[i][1] + bias0.y,
                     acc[i][2] + bias0.z, acc[i][3] + bias0.w};
        float4 v1 = {acc[i][4] + bias1.x, acc[i][5] + bias1.y,
                     acc[i][6] + bias1.z, acc[i][7] + bias1.w};
        *(float4*)(op + tn)      = v0;
        *(float4*)(op + tn + 64) = v1;
    }
}

// ---------------------------------------------------------------------------
// Recurrence v12 = v11 + in-wave shuffle reduce + 2 barriers/cycle + XCD
// co-location.
//
// Thread layout (unchanged math): kc=tid&15, u=tid>>4 -> the 16 k-chunks of
// unit u are 16 CONSECUTIVE LANES. After the per-lane matvec, a 4-stage
// __shfl_down(width=16) butterfly reduces the 4 gate sums in-wave; lane
// kc==0 does the cell update and publishes. This deletes the part[] LDS
// buffer, the owner waves, and 2 of v11's 4 barriers.
//
// Cycle (2 barriers):
//   S1: pollers (tid<256) poll b0 tag gt -> hsh0; updater lanes prefetch xv
//   barA
//   S2: all matvec b0 + shfl-reduce; kc==0: update c0, publish b0 tag gt+1
//   S3: (no barrier) pollers poll b1 tag gt -> hsh1
//   barC
//   S4: all matvec b1 + shfl-reduce; kc==0: update c1, publish b1 tag gt+1
// Hazard audit: hsh0 read in S2(t), next written in S1(t+1) - separated by
// barC(t). hsh1 written S3(t), read S4(t) - barC(t). hsh1 next written
// S3(t+1) after barA(t+1), S4(t) reads complete before barA(t+1). Publishes
// are single 8B atoms (tag|payload), no fence needed. Polls spin on remote
// tags only; remote wgs progress through their own barriers independently.
//
// XCD co-location: bid = xcd + 8*(q*4+s), G=q*8+xcd, layer=G>>5, bg=G&31.
// The 4 slice-wgs sharing mailbox (layer,bg) land on one XCD if XCD =
// bid%8 (round-robin heuristic). Correct under ANY mapping; faster if
// agent atomics resolve intra-XCD.
// ---------------------------------------------------------------------------
#define MBSTRIDE ((size_t)BATCH * HID)   // ulongs per parity block

__device__ __forceinline__ float sigmoid_f(float x) {
    return 1.f / (1.f + __expf(-x));
}
__device__ __forceinline__ float tanh_f(float x) {
    return 1.f - 2.f / (1.f + __expf(2.f * x));
}

__global__ __launch_bounds__(1024, 4)
void lstm_rec_v12(const float* __restrict__ xg1, const float* __restrict__ xg2,
                  const float* __restrict__ w_hh, const float* __restrict__ b_hh,
                  unsigned long long* mb1, unsigned long long* mb2,
                  float* __restrict__ cs1, float* __restrict__ cs2,
                  float* __restrict__ h1ch,
                  int CH, int gbaseA, int gbaseB, int doA, int doB)
{
    // h(t-1) per phase: 16 chunks of 16 floats padded to 20 (bank-spread)
    __shared__ __attribute__((aligned(16))) float hsh[2][16 * 20];

    const int bid = blockIdx.x;
    // XCD co-location decode (bijective): bid = xcd + 8*(q*4 + s)
    const int xcd   = bid & 7;
    const int mm    = bid >> 3;
    const int s     = mm & 3;             // slice: units [s*64, s*64+64)
    const int G     = (mm >> 2) * 8 + xcd;
    const int layer = G >> 5;             // == bid>>7 under this encoding
    const int b0    = (G & 31) * 2;       // batches {b0, b0+1}
    if (layer == 0 && !doA) return;
    if (layer == 1 && !doB) return;

    const int tid = threadIdx.x;
    const int kc  = tid & 15;            // k-chunk of 16 (consecutive lanes)
    const int u   = tid >> 4;            // unit 0..63
    const int gu  = s * 64 + u;

    const float* xgL = layer ? xg2 : xg1;
    const float* wL  = w_hh + (size_t)layer * GATES * HID;
    const float* bL  = b_hh + layer * GATES;
    unsigned long long* mbL = layer ? mb2 : mb1;
    float* csL = layer ? cs2 : cs1;
    const int gbase = layer ? gbaseB : gbaseA;

    // ---- one-time: 4 gate-rows x 16 weights into registers, laundered ----
    float4 wreg[4][4];
    #pragma unroll
    for (int j = 0; j < 4; ++j) {
        const float* wr = wL + (size_t)(j * 256 + gu) * HID + kc * 16;
        #pragma unroll
        for (int i = 0; i < 4; ++i) {
            float4 w = *(const float4*)(wr + 4 * i);
            asm volatile("" : "+v"(w.x), "+v"(w.y), "+v"(w.z), "+v"(w.w));
            wreg[j][i] = w;
        }
    }

    // ---- updater lanes (kc==0): both batches' cell state + biases ----
    const bool upd = (kc == 0);
    float c0 = 0.f, c1 = 0.f;
    float bh[4] = {0.f, 0.f, 0.f, 0.f};
    if (upd) {
        c0 = csL[b0 * HID + gu];
        c1 = csL[(b0 + 1) * HID + gu];
        #pragma unroll
        for (int g = 0; g < 4; ++g) bh[g] = bL[g * 256 + gu];
    }

    for (int t = 0; t < CH; ++t) {
        const int gt = gbase + t;
        const int pr = gt & 1;

        // ---- S1: updaters prefetch xv (both batches); pollers poll b0 ----
        float xv0[4], xv1[4];
        if (upd) {
            const float* xp0 = xgL + ((size_t)b0 * CH + t) * GATES;
            const float* xp1 = xgL + ((size_t)(b0 + 1) * CH + t) * GATES;
            #pragma unroll
            for (int g = 0; g < 4; ++g) xv0[g] = xp0[g * 256 + gu];
            #pragma unroll
            for (int g = 0; g < 4; ++g) xv1[g] = xp1[g * 256 + gu];
        }
        if (tid < 256) {
            const unsigned long long* slot =
                mbL + (size_t)pr * MBSTRIDE + b0 * HID + tid;
            unsigned long long w;
            do {
                w = __hip_atomic_load(slot, __ATOMIC_RELAXED,
                                      __HIP_MEMORY_SCOPE_AGENT);
            } while ((unsigned)(w >> 32) != (unsigned)gt);
            hsh[0][(tid >> 4) * 20 + (tid & 15)] = __uint_as_float((unsigned)w);
        }
        __syncthreads();   // barA: hsh0 ready

        // ---- S2: matvec b0 + in-wave reduce + update/publish ----
        {
            const float4* hq = (const float4*)&hsh[0][kc * 20];
            float4 h0 = hq[0], h1 = hq[1], h2 = hq[2], h3 = hq[3];
            float4 pv;
            float* pp = (float*)&pv;
            #pragma unroll
            for (int j = 0; j < 4; ++j) {
                float a = wreg[j][0].x * h0.x + wreg[j][0].y * h0.y
                        + wreg[j][0].z * h0.z + wreg[j][0].w * h0.w;
                a += wreg[j][1].x * h1.x + wreg[j][1].y * h1.y
                   + wreg[j][1].z * h1.z + wreg[j][1].w * h1.w;
                a += wreg[j][2].x * h2.x + wreg[j][2].y * h2.y
                   + wreg[j][2].z * h2.z + wreg[j][2].w * h2.w;
                a += wreg[j][3].x * h3.x + wreg[j][3].y * h3.y
                   + wreg[j][3].z * h3.z + wreg[j][3].w * h3.w;
                pp[j] = a;
            }
            #pragma unroll
            for (int off = 8; off > 0; off >>= 1) {
                pv.x += __shfl_down(pv.x, off, 16);
                pv.y += __shfl_down(pv.y, off, 16);
                pv.z += __shfl_down(pv.z, off, 16);
                pv.w += __shfl_down(pv.w, off, 16);
            }
            if (upd) {
                float ig = sigmoid_f(pv.x + xv0[0] + bh[0]);
                float fg = sigmoid_f(pv.y + xv0[1] + bh[1]);
                float gv = tanh_f   (pv.z + xv0[2] + bh[2]);
                float og = sigmoid_f(pv.w + xv0[3] + bh[3]);
                c0 = fg * c0 + ig * gv;
                float h = og * tanh_f(c0);
                __hip_atomic_store(
                    mbL + (size_t)((gt + 1) & 1) * MBSTRIDE + b0 * HID + gu,
                    ((unsigned long long)(unsigned)(gt + 1) << 32) |
                        (unsigned long long)__float_as_uint(h),
                    __ATOMIC_RELAXED, __HIP_MEMORY_SCOPE_AGENT);
                if (layer == 0)
                    h1ch[((size_t)b0 * CH + t) * HID + gu] = h;
            }
        }

        // ---- S3 (no barrier): pollers poll b1 ----
        if (tid < 256) {
            const unsigned long long* slot =
                mbL + (size_t)pr * MBSTRIDE + (b0 + 1) * HID + tid;
            unsigned long long w;
            do {
                w = __hip_atomic_load(slot, __ATOMIC_RELAXED,
                                      __HIP_MEMORY_SCOPE_AGENT);
            } while ((unsigned)(w >> 32) != (unsigned)gt);
            hsh[1][(tid >> 4) * 20 + (tid & 15)] = __uint_as_float((unsigned)w);
        }
        __syncthreads();   // barC: hsh1 ready; hsh0 free for S1(t+1)

        // ---- S4: matvec b1 + in-wave reduce + update/publish ----
        {
            const float4* hq = (const float4*)&hsh[1][kc * 20];
            float4 h0 = hq[0], h1 = hq[1], h2 = hq[2], h3 = hq[3];
            float4 pv;
            float* pp = (float*)&pv;
            #pragma unroll
            for (int j = 0; j < 4; ++j) {
                float a = wreg[j][0].x * h0.x + wreg[j][0].y * h0.y
                        + wreg[j][0].z * h0.z + wreg[j][0].w * h0.w;
                a += wreg[j][1].x * h1.x + wreg[j][1].y * h1.y
                   + wreg[j][1].z * h1.z + wreg[j][1].w * h1.w;
                a += wreg[j][2].x * h2.x + wreg[j][2].y * h2.y
                   + wreg[j][2].z * h2.z + wreg[j][2].w * h2.w;
                a += wreg[j][3].x * h3.x + wreg[j][3].y * h3.y
                   + wreg[j][3].z * h3.z + wreg[j][3].w * h3.w;
                pp[j] = a;
            }
            #pragma unroll
            for (int off = 8; off > 0; off >>= 1) {
                pv.x += __shfl_down(pv.x, off, 16);
                pv.y += __shfl_down(pv.y, off, 16);
                pv.z += __shfl_down(pv.z, off, 16);
                pv.w += __shfl_down(pv.w, off, 16);
            }
            if (upd) {
                float ig = sigmoid_f(pv.x + xv1[0] + bh[0]);
                float fg = sigmoid_f(pv.y + xv1[1] + bh[1]);
                float gv = tanh_f   (pv.z + xv1[2] + bh[2]);
                float og = sigmoid_f(pv.w + xv1[3] + bh[3]);
                c1 = fg * c1 + ig * gv;
                float h = og * tanh_f(c1);
                __hip_atomic_store(
                    mbL + (size_t)((gt + 1) & 1) * MBSTRIDE + (b0 + 1) * HID + gu,
                    ((unsigned long long)(unsigned)(gt + 1) << 32) |
                        (unsigned long long)__float_as_uint(h),
                    __ATOMIC_RELAXED, __HIP_MEMORY_SCOPE_AGENT);
                if (layer == 0)
                    h1ch[((size_t)(b0 + 1) * CH + t) * HID + gu] = h;
            }
        }
        // next S1 writes hsh0: protected by barC(t); next S3 writes hsh1:
        // protected by barA(t+1).
    }

    if (upd) {
        csL[b0 * HID + gu]       = c0;
        csL[(b0 + 1) * HID + gu] = c1;
    }
}

// ---------------------------------------------------------------------------
__global__ void final_linear(const unsigned long long* __restrict__ hw,
                             const float* __restrict__ w_lin,
                             const float* __restrict__ b_lin,
                             float* __restrict__ out)
{
    int b = blockIdx.x;
    int l = threadIdx.x;
    float p = 0.f;
    #pragma unroll
    for (int j = 0; j < 4; ++j) {
        int u = l + j * 64;
        p += __uint_as_float((unsigned)hw[b * HID + u]) * w_lin[u];
    }
    #pragma unroll
    for (int off = 32; off > 0; off >>= 1) p += __shfl_down(p, off, 64);
    if (l == 0) out[b] = p + b_lin[0];
}

// ---------------------------------------------------------------------------
extern "C" void kernel_launch(void* const* d_in, const int* in_sizes, int n_in,
                              void* d_out, int out_size, void* d_ws, size_t ws_size,
                              hipStream_t stream)
{
    const float* input = (const float*)d_in[0];
    const float* w_ih  = (const float*)d_in[1];
    const float* w_hh  = (const float*)d_in[2];
    const float* b_ih  = (const float*)d_in[3];
    const float* b_hh  = (const float*)d_in[4];
    const float* w_lin = (const float*)d_in[5];
    const float* b_lin = (const float*)d_in[6];
    float* out = (float*)d_out;

    const size_t c_elems  = (size_t)BATCH * HID;
    const size_t mb_bytes = 2 * MBSTRIDE * sizeof(unsigned long long);
    char*  ws   = (char*)d_ws;
    float* cs1  = (float*)ws;
    float* cs2  = cs1 + c_elems;
    unsigned long long* mb1 = (unsigned long long*)(cs2 + c_elems);
    unsigned long long* mb2 = mb1 + 2 * MBSTRIDE;
    const size_t zero_bytes = 2 * c_elems * 4 + 2 * mb_bytes;
    float* big  = (float*)(ws + ((zero_bytes + 255) & ~(size_t)255));

    int CH = 256;   // fit-checked; falls back if ws_size is smaller
    while (CH > 16) {
        size_t need = ((zero_bytes + 255) & ~(size_t)255)
                    + ((size_t)2 * BATCH * CH * GATES + (size_t)BATCH * CH * HID) * 4;
        if (need <= ws_size) break;
        CH >>= 1;
    }
    const int ch_log2 = __builtin_ctz((unsigned)CH);

    float* xg1  = big;
    float* xg2  = xg1 + (size_t)BATCH * CH * GATES;
    float* h1ch = xg2 + (size_t)BATCH * CH * GATES;

    hipMemsetAsync(ws, 0, zero_bytes, stream);

    const int NC = SEQ / CH;
    dim3 gblk(BATCH * CH / BM, GATES / BN);

    // chunk-lag pipeline: dispatch c runs layer-1 on chunk c (bids 0..127)
    // and layer-2 on chunk c-1 (bids 128..255) concurrently; GEMM2(c-1)
    // consumes h1ch written by the previous rec dispatch.
    for (int c = 0; c <= NC; ++c) {
        if (c < NC)
            xg_gemm<<<gblk, 256, 0, stream>>>(input + (size_t)c * CH * HID, w_ih,
                                              b_ih, xg1, SEQ * HID, ch_log2);
        if (c >= 1)
            xg_gemm<<<gblk, 256, 0, stream>>>(h1ch, w_ih + (size_t)GATES * HID,
                                              b_ih + GATES, xg2, CH * HID, ch_log2);
        lstm_rec_v12<<<256, 1024, 0, stream>>>(xg1, xg2, w_hh, b_hh, mb1, mb2,
                                               cs1, cs2, h1ch, CH,
                                               c * CH, (c - 1) * CH,
                                               (c < NC) ? 1 : 0, (c >= 1) ? 1 : 0);
    }

    // last h2 (step 2047, tag 2048) sits in mb2 parity-0 block
    final_linear<<<BATCH, 64, 0, stream>>>(mb2, w_lin, b_lin, out);
}

// Round 7
// 6244.890 us; speedup vs baseline: 1.2509x; 1.2509x over previous
//
#include <hip/hip_runtime.h>
#include <math.h>

#define HID   256
#define GATES 1024   // 4*HID
#define BATCH 64
#define SEQ   2048

// ---------------------------------------------------------------------------
// GEMM: out[r][g] = sum_k A_row(r)[k] * W[g][k] + bias[g]   (unchanged, proven)
// ---------------------------------------------------------------------------
#define BM 128
#define BN 128
#define BK 16
#define LDP 132

__global__ __launch_bounds__(256, 2)
void xg_gemm(const float* __restrict__ A, const float* __restrict__ W,
             const float* __restrict__ bias, float* __restrict__ out,
             int a_bstride, int ch_log2)
{
    __shared__ float As[BK][LDP];
    __shared__ float Ws[BK][LDP];

    const int tid   = threadIdx.x;
    const int m_blk = blockIdx.x * BM;
    const int n_blk = blockIdx.y * BN;

    const int tn = (tid & 15) * 4;
    const int tm = (tid >> 4) * 4;

    float acc[8][8];
    #pragma unroll
    for (int i = 0; i < 8; ++i)
        #pragma unroll
        for (int j = 0; j < 8; ++j) acc[i][j] = 0.f;

    const int lrow = tid >> 2;
    const int lkc  = (tid & 3) * 4;
    const int CHm1 = (1 << ch_log2) - 1;

    for (int k0 = 0; k0 < HID; k0 += BK) {
        #pragma unroll
        for (int p = 0; p < 2; ++p) {
            int row = p * 64 + lrow;
            int r   = m_blk + row;
            int b   = r >> ch_log2;
            int t   = r & CHm1;
            const float4 a = *(const float4*)(A + (size_t)b * a_bstride +
                                              (size_t)t * HID + k0 + lkc);
            As[lkc + 0][row] = a.x;
            As[lkc + 1][row] = a.y;
            As[lkc + 2][row] = a.z;
            As[lkc + 3][row] = a.w;

            int g = n_blk + row;
            const float4 w = *(const float4*)(W + (size_t)g * HID + k0 + lkc);
            Ws[lkc + 0][row] = w.x;
            Ws[lkc + 1][row] = w.y;
            Ws[lkc + 2][row] = w.z;
            Ws[lkc + 3][row] = w.w;
        }
        __syncthreads();

        #pragma unroll
        for (int kk = 0; kk < BK; ++kk) {
            float4 a0 = *(const float4*)&As[kk][tm];
            float4 a1 = *(const float4*)&As[kk][tm + 64];
            float4 b0 = *(const float4*)&Ws[kk][tn];
            float4 b1 = *(const float4*)&Ws[kk][tn + 64];
            float av[8] = {a0.x, a0.y, a0.z, a0.w, a1.x, a1.y, a1.z, a1.w};
            float bv[8] = {b0.x, b0.y, b0.z, b0.w, b1.x, b1.y, b1.z, b1.w};
            #pragma unroll
            for (int i = 0; i < 8; ++i)
                #pragma unroll
                for (int j = 0; j < 8; ++j)
                    acc[i][j] += av[i] * bv[j];
        }
        __syncthreads();
    }

    const float4 bias0 = *(const float4*)&bias[n_blk + tn];
    const float4 bias1 = *(const float4*)&bias[n_blk + tn + 64];
    #pragma unroll
    for (int i = 0; i < 8; ++i) {
        int m  = (i < 4) ? (tm + i) : (tm + 60 + i);
        int gm = m_blk + m;
        float* op = out + (size_t)gm * GATES + n_blk;
        float4 v0 = {acc[i][0] + bias0.x, acc[i][1] + bias0.y,
                     acc[i][2] + bias0.z, acc[i][3] + bias0.w};
        float4 v1 = {acc[i][4] + bias1.x, acc[i][5] + bias1.y,
                     acc[i][6] + bias1.z, acc[i][7] + bias1.w};
        *(float4*)(op + tn)      = v0;
        *(float4*)(op + tn + 64) = v1;
    }
}

// ---------------------------------------------------------------------------
// Recurrence v13 = v11 body (proven 535us/dispatch) + XCD co-location remap
// (the ONE variable v12 was supposed to test before the shuffle regression
// confounded it).
//
// v11 cycle (4 barriers, LDS part reduce, dedicated owner/poller waves):
//   S1: w1 finishes b1(t-1) [reduce part1 + publish]; pollers poll b0(t)
//   barA | S2: all matvec b0 -> part0 | barB
//   S3: w0 reduces part0, publishes b0(t); pollers poll b1(t)
//   barC | S4: all matvec b1 -> part1 | barD
// v12 lesson: do NOT replace the part-LDS reduce with shfl butterflies
// (ds_bpermute chains doubled VALU work -> VALUBusy 91%, +37% cycle).
//
// XCD co-location: bid = xcd + 8*(q*4+s); G = q*8+xcd; layer=G>>5,
// b0=(G&31)*2, slice=s. The 4 slice-wgs sharing mailbox group (layer,b0)
// have bids congruent mod 8 -> same XCD under round-robin dispatch ->
// their mailbox lines can stay in one XCD's L2. Correct under ANY mapping.
// ---------------------------------------------------------------------------
#define MBSTRIDE ((size_t)BATCH * HID)   // ulongs per parity block

__device__ __forceinline__ float sigmoid_f(float x) {
    return 1.f / (1.f + __expf(-x));
}
__device__ __forceinline__ float tanh_f(float x) {
    return 1.f - 2.f / (1.f + __expf(2.f * x));
}

__global__ __launch_bounds__(1024, 4)
void lstm_rec_v13(const float* __restrict__ xg1, const float* __restrict__ xg2,
                  const float* __restrict__ w_hh, const float* __restrict__ b_hh,
                  unsigned long long* mb1, unsigned long long* mb2,
                  float* __restrict__ cs1, float* __restrict__ cs2,
                  float* __restrict__ h1ch,
                  int CH, int gbaseA, int gbaseB, int doA, int doB)
{
    // h(t-1) per phase: 16 chunks of 16 floats padded to 20 (v7 layout)
    __shared__ __attribute__((aligned(16))) float hsh[2][16 * 20];
    // partials double-buffered per phase: part[ph][kc][4u+j]
    __shared__ __attribute__((aligned(16))) float part[2][16][260];
    // occupancy pad (best-effort; v11 ran fine at this footprint)
    __shared__ float occ_pad[3328];

    const int bid = blockIdx.x;
    // XCD co-location decode (bijective): bid = xcd + 8*(q*4 + s)
    const int xcd   = bid & 7;
    const int mm    = bid >> 3;
    const int s     = mm & 3;             // slice: units [s*64, s*64+64)
    const int G     = (mm >> 2) * 8 + xcd;
    const int layer = G >> 5;
    const int b0    = (G & 31) * 2;       // batches {b0, b0+1}
    if (layer == 0 && !doA) return;
    if (layer == 1 && !doB) return;

    // keep occ_pad alive: runtime-unprovable guard + volatile accesses
    if (gbaseA == 0x7fffffff) {
        volatile float* vp = occ_pad;
        vp[threadIdx.x] = (float)CH;
        cs1[0] = vp[threadIdx.x ^ 1];
    }

    const int tid = threadIdx.x;
    const int kc  = tid & 15;            // k-chunk of 16
    const int u   = tid >> 4;            // unit 0..63
    const int gu  = s * 64 + u;

    const float* xgL = layer ? xg2 : xg1;
    const float* wL  = w_hh + (size_t)layer * GATES * HID;
    const float* bL  = b_hh + layer * GATES;
    unsigned long long* mbL = layer ? mb2 : mb1;
    float* csL = layer ? cs2 : cs1;
    const int gbase = layer ? gbaseB : gbaseA;

    // ---- one-time: 4 gate-rows x 16 weights into registers, laundered ----
    float4 wreg[4][4];
    #pragma unroll
    for (int j = 0; j < 4; ++j) {
        const float* wr = wL + (size_t)(j * 256 + gu) * HID + kc * 16;
        #pragma unroll
        for (int i = 0; i < 4; ++i) {
            float4 w = *(const float4*)(wr + 4 * i);
            asm volatile("" : "+v"(w.x), "+v"(w.y), "+v"(w.z), "+v"(w.w));
            wreg[j][i] = w;
        }
    }

    // ---- owner identity: wave0 -> batch b0 (phase 0), wave1 -> b0+1 ----
    const int u_o  = tid & 63;
    const int gu_o = s * 64 + u_o;
    const int b_o  = b0 + ((tid >> 6) & 1);   // valid for tid<128
    float c_u = 0.f;
    float bh[4] = {0.f, 0.f, 0.f, 0.f};
    float xv[4] = {0.f, 0.f, 0.f, 0.f};
    if (tid < 128) {
        c_u = csL[b_o * HID + gu_o];
        #pragma unroll
        for (int g = 0; g < 4; ++g) bh[g] = bL[g * 256 + gu_o];
    }

    // ---- poller identity: waves 12-15, slot pt in [0,256) ----
    const int pt = tid - 768;

    for (int t = 0; t < CH; ++t) {
        const int gt = gbase + t;
        const int pr = gt & 1;

        // ================= S1 =================
        if (tid >= 768) {
            // poll b0 h(t-1), tag gt (published by w0 in S3 of prev cycle)
            const unsigned long long* slot =
                mbL + (size_t)pr * MBSTRIDE + b0 * HID + pt;
            unsigned long long w;
            do {
                w = __hip_atomic_load(slot, __ATOMIC_RELAXED,
                                      __HIP_MEMORY_SCOPE_AGENT);
            } while ((unsigned)(w >> 32) != (unsigned)gt);
            hsh[0][(pt >> 4) * 20 + (pt & 15)] = __uint_as_float((unsigned)w);
        } else if (tid < 128) {
            if ((tid & 64) && t > 0) {
                // w1: finish b1 step t-1: reduce part1, update, publish tag gt
                float gx = 0.f, gy = 0.f, gz = 0.f, gw = 0.f;
                #pragma unroll
                for (int k = 0; k < 16; ++k) {
                    float4 pk = *(const float4*)&part[1][k][4 * u_o];
                    gx += pk.x; gy += pk.y; gz += pk.z; gw += pk.w;
                }
                float ig = sigmoid_f(gx + xv[0] + bh[0]);
                float fg = sigmoid_f(gy + xv[1] + bh[1]);
                float gv = tanh_f   (gz + xv[2] + bh[2]);
                float og = sigmoid_f(gw + xv[3] + bh[3]);
                c_u = fg * c_u + ig * gv;
                float h = og * tanh_f(c_u);
                __hip_atomic_store(
                    mbL + (size_t)(gt & 1) * MBSTRIDE + b_o * HID + gu_o,
                    ((unsigned long long)(unsigned)gt << 32) |
                        (unsigned long long)__float_as_uint(h),
                    __ATOMIC_RELAXED, __HIP_MEMORY_SCOPE_AGENT);
                if (layer == 0)
                    h1ch[((size_t)b_o * CH + (t - 1)) * HID + gu_o] = h;
            }
            // owners (both waves): prefetch xv(t) for own batch
            const float* xp = xgL + ((size_t)b_o * CH + t) * GATES;
            #pragma unroll
            for (int g = 0; g < 4; ++g) xv[g] = xp[g * 256 + gu_o];
        }
        __syncthreads();   // barA: hsh0 ready; part1(t-1) consumed

        // ================= S2: matvec b0 -> part0 =================
        {
            const float4* hq = (const float4*)&hsh[0][kc * 20];
            float4 h0 = hq[0], h1 = hq[1], h2 = hq[2], h3 = hq[3];
            float4 pv;
            float* pp = (float*)&pv;
            #pragma unroll
            for (int j = 0; j < 4; ++j) {
                float a = wreg[j][0].x * h0.x + wreg[j][0].y * h0.y
                        + wreg[j][0].z * h0.z + wreg[j][0].w * h0.w;
                a += wreg[j][1].x * h1.x + wreg[j][1].y * h1.y
                   + wreg[j][1].z * h1.z + wreg[j][1].w * h1.w;
                a += wreg[j][2].x * h2.x + wreg[j][2].y * h2.y
                   + wreg[j][2].z * h2.z + wreg[j][2].w * h2.w;
                a += wreg[j][3].x * h3.x + wreg[j][3].y * h3.y
                   + wreg[j][3].z * h3.z + wreg[j][3].w * h3.w;
                pp[j] = a;
            }
            *(float4*)&part[0][kc][4 * u] = pv;
        }
        __syncthreads();   // barB: part0 ready

        // ================= S3 =================
        if (tid < 64) {
            // w0: finish b0 step t: reduce part0, update, publish tag gt+1
            float gx = 0.f, gy = 0.f, gz = 0.f, gw = 0.f;
            #pragma unroll
            for (int k = 0; k < 16; ++k) {
                float4 pk = *(const float4*)&part[0][k][4 * u_o];
                gx += pk.x; gy += pk.y; gz += pk.z; gw += pk.w;
            }
            float ig = sigmoid_f(gx + xv[0] + bh[0]);
            float fg = sigmoid_f(gy + xv[1] + bh[1]);
            float gv = tanh_f   (gz + xv[2] + bh[2]);
            float og = sigmoid_f(gw + xv[3] + bh[3]);
            c_u = fg * c_u + ig * gv;
            float h = og * tanh_f(c_u);
            __hip_atomic_store(
                mbL + (size_t)((gt + 1) & 1) * MBSTRIDE + b_o * HID + gu_o,
                ((unsigned long long)(unsigned)(gt + 1) << 32) |
                    (unsigned long long)__float_as_uint(h),
                __ATOMIC_RELAXED, __HIP_MEMORY_SCOPE_AGENT);
            if (layer == 0)
                h1ch[((size_t)b_o * CH + t) * HID + gu_o] = h;
        } else if (tid >= 768) {
            // poll b1 h(t-1), tag gt (published by w1 in S1 of THIS cycle)
            const unsigned long long* slot =
                mbL + (size_t)pr * MBSTRIDE + (b0 + 1) * HID + pt;
            unsigned long long w;
            do {
                w = __hip_atomic_load(slot, __ATOMIC_RELAXED,
                                      __HIP_MEMORY_SCOPE_AGENT);
            } while ((unsigned)(w >> 32) != (unsigned)gt);
            hsh[1][(pt >> 4) * 20 + (pt & 15)] = __uint_as_float((unsigned)w);
        }
        __syncthreads();   // barC: hsh1 ready; part0 consumed

        // ================= S4: matvec b1 -> part1 =================
        {
            const float4* hq = (const float4*)&hsh[1][kc * 20];
            float4 h0 = hq[0], h1 = hq[1], h2 = hq[2], h3 = hq[3];
            float4 pv;
            float* pp = (float*)&pv;
            #pragma unroll
            for (int j = 0; j < 4; ++j) {
                float a = wreg[j][0].x * h0.x + wreg[j][0].y * h0.y
                        + wreg[j][0].z * h0.z + wreg[j][0].w * h0.w;
                a += wreg[j][1].x * h1.x + wreg[j][1].y * h1.y
                   + wreg[j][1].z * h1.z + wreg[j][1].w * h1.w;
                a += wreg[j][2].x * h2.x + wreg[j][2].y * h2.y
                   + wreg[j][2].z * h2.z + wreg[j][2].w * h2.w;
                a += wreg[j][3].x * h3.x + wreg[j][3].y * h3.y
                   + wreg[j][3].z * h3.z + wreg[j][3].w * h3.w;
                pp[j] = a;
            }
            *(float4*)&part[1][kc][4 * u] = pv;
        }
        __syncthreads();   // barD: part1 ready -> consumed next S1
    }

    // ---- epilogue: w1 finishes b1 step CH-1 (tag gbase+CH) ----
    if (tid >= 64 && tid < 128) {
        const int gt_e = gbase + CH;
        float gx = 0.f, gy = 0.f, gz = 0.f, gw = 0.f;
        #pragma unroll
        for (int k = 0; k < 16; ++k) {
            float4 pk = *(const float4*)&part[1][k][4 * u_o];
            gx += pk.x; gy += pk.y; gz += pk.z; gw += pk.w;
        }
        float ig = sigmoid_f(gx + xv[0] + bh[0]);
        float fg = sigmoid_f(gy + xv[1] + bh[1]);
        float gv = tanh_f   (gz + xv[2] + bh[2]);
        float og = sigmoid_f(gw + xv[3] + bh[3]);
        c_u = fg * c_u + ig * gv;
        float h = og * tanh_f(c_u);
        __hip_atomic_store(
            mbL + (size_t)(gt_e & 1) * MBSTRIDE + b_o * HID + gu_o,
            ((unsigned long long)(unsigned)gt_e << 32) |
                (unsigned long long)__float_as_uint(h),
            __ATOMIC_RELAXED, __HIP_MEMORY_SCOPE_AGENT);
        if (layer == 0)
            h1ch[((size_t)b_o * CH + (CH - 1)) * HID + gu_o] = h;
    }

    if (tid < 128) csL[b_o * HID + gu_o] = c_u;
}

// ---------------------------------------------------------------------------
__global__ void final_linear(const unsigned long long* __restrict__ hw,
                             const float* __restrict__ w_lin,
                             const float* __restrict__ b_lin,
                             float* __restrict__ out)
{
    int b = blockIdx.x;
    int l = threadIdx.x;
    float p = 0.f;
    #pragma unroll
    for (int j = 0; j < 4; ++j) {
        int u = l + j * 64;
        p += __uint_as_float((unsigned)hw[b * HID + u]) * w_lin[u];
    }
    #pragma unroll
    for (int off = 32; off > 0; off >>= 1) p += __shfl_down(p, off, 64);
    if (l == 0) out[b] = p + b_lin[0];
}

// ---------------------------------------------------------------------------
extern "C" void kernel_launch(void* const* d_in, const int* in_sizes, int n_in,
                              void* d_out, int out_size, void* d_ws, size_t ws_size,
                              hipStream_t stream)
{
    const float* input = (const float*)d_in[0];
    const float* w_ih  = (const float*)d_in[1];
    const float* w_hh  = (const float*)d_in[2];
    const float* b_ih  = (const float*)d_in[3];
    const float* b_hh  = (const float*)d_in[4];
    const float* w_lin = (const float*)d_in[5];
    const float* b_lin = (const float*)d_in[6];
    float* out = (float*)d_out;

    const size_t c_elems  = (size_t)BATCH * HID;
    const size_t mb_bytes = 2 * MBSTRIDE * sizeof(unsigned long long);
    char*  ws   = (char*)d_ws;
    float* cs1  = (float*)ws;
    float* cs2  = cs1 + c_elems;
    unsigned long long* mb1 = (unsigned long long*)(cs2 + c_elems);
    unsigned long long* mb2 = mb1 + 2 * MBSTRIDE;
    const size_t zero_bytes = 2 * c_elems * 4 + 2 * mb_bytes;
    float* big  = (float*)(ws + ((zero_bytes + 255) & ~(size_t)255));

    int CH = 256;   // fit-checked; falls back if ws_size is smaller
    while (CH > 16) {
        size_t need = ((zero_bytes + 255) & ~(size_t)255)
                    + ((size_t)2 * BATCH * CH * GATES + (size_t)BATCH * CH * HID) * 4;
        if (need <= ws_size) break;
        CH >>= 1;
    }
    const int ch_log2 = __builtin_ctz((unsigned)CH);

    float* xg1  = big;
    float* xg2  = xg1 + (size_t)BATCH * CH * GATES;
    float* h1ch = xg2 + (size_t)BATCH * CH * GATES;

    hipMemsetAsync(ws, 0, zero_bytes, stream);

    const int NC = SEQ / CH;
    dim3 gblk(BATCH * CH / BM, GATES / BN);

    // chunk-lag pipeline: dispatch c runs layer-1 on chunk c and layer-2 on
    // chunk c-1 concurrently; GEMM2(c-1) consumes h1ch from the previous
    // rec dispatch.
    for (int c = 0; c <= NC; ++c) {
        if (c < NC)
            xg_gemm<<<gblk, 256, 0, stream>>>(input + (size_t)c * CH * HID, w_ih,
                                              b_ih, xg1, SEQ * HID, ch_log2);
        if (c >= 1)
            xg_gemm<<<gblk, 256, 0, stream>>>(h1ch, w_ih + (size_t)GATES * HID,
                                              b_ih + GATES, xg2, CH * HID, ch_log2);
        lstm_rec_v13<<<256, 1024, 0, stream>>>(xg1, xg2, w_hh, b_hh, mb1, mb2,
                                               cs1, cs2, h1ch, CH,
                                               c * CH, (c - 1) * CH,
                                               (c < NC) ? 1 : 0, (c >= 1) ? 1 : 0);
    }

    // last h2 (step 2047, tag 2048) sits in mb2 parity-0 block
    final_linear<<<BATCH, 64, 0, stream>>>(mb2, w_lin, b_lin, out);
}